// Round 12
// baseline (3403.810 us; speedup 1.0000x reference)
//
#include <hip/hip_runtime.h>
#include <math.h>

#define NBLK   256
#define NTHR   512
#define TSTEPS 512

typedef float        f32x4  __attribute__((ext_vector_type(4)));
typedef unsigned int u32x4  __attribute__((ext_vector_type(4)));
typedef short        bf16x8 __attribute__((ext_vector_type(8)));

union UAB { u32x4 u; bf16x8 s; };

// ---------------- ws (u32 units) ----------------
//   th_pair[g=4][buf=2][b=16][K=1024] u32  (hi bf16 in top 16, lo bf16 in low 16)
//   slots[256] ints @ 131072   (poisoned 0xAA.. = negative, OK for ">= t+1" waits)

// ---------------- LDS (float units) ----------------
// BF    [kc=32][T=2][hl=2][lane=64][4 u32]   @ 0       (131072 B)  MFMA B-fragments
// wo_l  [2][1024] f32                        @ 32768   (8 KB)
// redf  [8 waves][512] f32                   @ 34816   (16 KB)  C-tile partials
// po_f  [8 waves][32] f32                    @ 38912   (1 KB)   o-proj partials
// h_lds [256] f32                            @ 39712
// bu[16] @ 39968  br[16] @ 39984  bo[2] @ 40000
#define WO_F   32768
#define RED_F  34816
#define PO_F   38912
#define HL_F   39712
#define BU_F   39968
#define BR_F   39984
#define BO_F   40000
#define SMEM_FLOATS 40002
#define SMEM_BYTES  (SMEM_FLOATS * 4)

#define LDA(ua, ub, p)                                                    \
  asm volatile(                                                           \
    "global_load_dwordx4 %0, %2, off sc0 sc1\n\t"                         \
    "global_load_dwordx4 %1, %2, off offset:16 sc0 sc1"                   \
    : "=&v"(ua), "=&v"(ub) : "v"(p) : "memory")

__device__ __forceinline__ void stu_mall(unsigned int* p, unsigned int v) {
  asm volatile("global_store_dword %0, %1, off sc0 sc1" :: "v"(p), "v"(v) : "memory");
}

// One K=32 chunk: wait its A pair, unpack hi/lo frags, 6 MFMAs, o-proj VALU.
#define PROC_KC(KCL, VM, ua, ub)                                          \
  {                                                                       \
    asm volatile("s_waitcnt vmcnt(" #VM ")"                               \
                 : "+v"(ua), "+v"(ub) :: "memory");                       \
    const int kcg = w_ * 4 + KCL;                                         \
    UAB Ah, Al;                                                           \
    Ah.u[0] = (ua[1] & 0xffff0000u) | (ua[0] >> 16);                      \
    Ah.u[1] = (ua[3] & 0xffff0000u) | (ua[2] >> 16);                      \
    Ah.u[2] = (ub[1] & 0xffff0000u) | (ub[0] >> 16);                      \
    Ah.u[3] = (ub[3] & 0xffff0000u) | (ub[2] >> 16);                      \
    Al.u[0] = (ua[1] << 16) | (ua[0] & 0xffffu);                          \
    Al.u[1] = (ua[3] << 16) | (ua[2] & 0xffffu);                          \
    Al.u[2] = (ub[1] << 16) | (ub[0] & 0xffffu);                          \
    Al.u[3] = (ub[3] << 16) | (ub[2] & 0xffffu);                          \
    bf16x8 bUh = Bf[(kcg * 4 + 0) * 64 + lane];                           \
    bf16x8 bUl = Bf[(kcg * 4 + 1) * 64 + lane];                           \
    bf16x8 bRh = Bf[(kcg * 4 + 2) * 64 + lane];                           \
    bf16x8 bRl = Bf[(kcg * 4 + 3) * 64 + lane];                           \
    accU = __builtin_amdgcn_mfma_f32_16x16x32_bf16(Ah.s, bUh, accU,0,0,0);\
    accU = __builtin_amdgcn_mfma_f32_16x16x32_bf16(Ah.s, bUl, accU,0,0,0);\
    accU = __builtin_amdgcn_mfma_f32_16x16x32_bf16(Al.s, bUh, accU,0,0,0);\
    accR = __builtin_amdgcn_mfma_f32_16x16x32_bf16(Ah.s, bRh, accR,0,0,0);\
    accR = __builtin_amdgcn_mfma_f32_16x16x32_bf16(Ah.s, bRl, accR,0,0,0);\
    accR = __builtin_amdgcn_mfma_f32_16x16x32_bf16(Al.s, bRh, accR,0,0,0);\
    _Pragma("unroll")                                                     \
    for (int j = 0; j < 8; ++j) {                                         \
      unsigned int uw = (j < 4) ? ua[j] : ub[j - 4];                      \
      float tf = __uint_as_float(uw & 0xffff0000u)                        \
               + __uint_as_float(uw << 16);                               \
      int kidx = kcg * 32 + kb8 + j;                                      \
      po0 = fmaf(wo_l[kidx], tf, po0);                                    \
      po1 = fmaf(wo_l[1024 + kidx], tf, po1);                             \
    }                                                                     \
  }

__global__ __launch_bounds__(NTHR) void ugrnn_persist(
    const float* __restrict__ x,
    const float* __restrict__ h_init,
    const float* __restrict__ w_o,
    const float* __restrict__ b_o,
    const float* __restrict__ w_u,
    const float* __restrict__ b_u,
    const float* __restrict__ w_r,
    const float* __restrict__ b_r,
    float* __restrict__ ws,
    float* __restrict__ out)
{
  extern __shared__ float smem[];
  unsigned int* BFu  = (unsigned int*)smem;
  const bf16x8* Bf   = (const bf16x8*)smem;
  float* wo_l  = smem + WO_F;
  float* redf  = smem + RED_F;
  float* po_f  = smem + PO_F;
  float* h_lds = smem + HL_F;
  float* bu_l  = smem + BU_F;
  float* br_l  = smem + BR_F;
  float* bo_l  = smem + BO_F;

  const int tid = threadIdx.x;
  const int blk = blockIdx.x;
  const int g   = blk >> 6;        // batch group: rows 16g .. 16g+15
  const int cb  = blk & 63;        // state-column block: cols 16cb .. 16cb+15
  const int sg0 = cb * 16;

  unsigned int* thp_base = (unsigned int*)ws;         // th_pair buffers
  int* slots = (int*)(thp_base + 131072);

  // ---------------- one-time setup ----------------
  // MFMA B-fragments for w_u/w_r hi+lo.  Frag: lane l -> n=l&15, k=(l>>4)*8+j.
  // 16384 items = kc(32) x T(2) x lane(64) x r(4); each writes hi and lo word.
  for (int widx = tid; widx < 16384; widx += NTHR) {
    int r  = widx & 3;
    int l  = (widx >> 2) & 63;
    int T  = (widx >> 8) & 1;
    int kc = widx >> 9;
    int n  = l & 15, kb = l >> 4;
    int Ka = kc * 32 + kb * 8 + 2 * r;
    const float* Wsrc = T ? w_r : w_u;
    float wa = Wsrc[(size_t)Ka * 1024 + sg0 + n];
    float wb = Wsrc[(size_t)(Ka + 1) * 1024 + sg0 + n];
    unsigned int ha = __float_as_uint(wa) & 0xffff0000u;
    unsigned int hb = __float_as_uint(wb) & 0xffff0000u;
    unsigned int la = __float_as_uint(wa - __uint_as_float(ha)) >> 16;
    unsigned int lb = __float_as_uint(wb - __uint_as_float(hb)) >> 16;
    unsigned int base = kc * 1024 + T * 512 + l * 4 + r;
    BFu[base]       = hb | (ha >> 16);      // hi frag word (j=2r+1 high, j=2r low)
    BFu[base + 256] = (lb << 16) | la;      // lo frag word
  }
  for (int idx = tid; idx < 2048; idx += NTHR) {
    int o = idx >> 10, K = idx & 1023;
    wo_l[idx] = w_o[(size_t)(2 * cb + o) * 1024 + K];
  }
  if (tid < 16) { bu_l[tid] = b_u[sg0 + tid]; br_l[tid] = b_r[sg0 + tid]; }
  if (tid < 2)  { bo_l[tid] = b_o[2 * cb + tid]; }

  // h + th0 (packed hi|lo) ; th_pair[g][buf][b][K]
  if (tid < 256) {
    int b = tid >> 4, sl = tid & 15;
    float hv = h_init[(size_t)(g * 16 + b) * 1024 + sg0 + sl];
    h_lds[tid] = hv;
    float th = tanhf(hv);
    unsigned int hbits = __float_as_uint(th) & 0xffff0000u;
    float lof = th - __uint_as_float(hbits);
    unsigned int pk = hbits | (__float_as_uint(lof) >> 16);
    stu_mall(thp_base + (size_t)(g * 2 + 0) * 16384 + b * 1024 + sg0 + sl, pk);
  }
  asm volatile("s_waitcnt vmcnt(0)" ::: "memory");
  __syncthreads();
  if (tid == 0)
    __hip_atomic_store(&slots[blk], 1, __ATOMIC_RELAXED, __HIP_MEMORY_SCOPE_AGENT);

  // ---------------- per-lane constants ----------------
  const int w_   = tid >> 6;          // wave 0..7 -> K-slice [128w, 128w+128)
  const int lane = tid & 63;
  const int kb8  = (lane >> 4) * 8;   // k sub-offset within K=32 chunk

  // ---------------- scan ----------------
  for (int t = 0; t <= TSTEPS; ++t) {
    // prefetch x for the (t-1) error output BEFORE the poll: its HBM latency
    // hides under the poll window instead of sitting in the vmcnt chain.
    float xv = 0.f; int oi = 0, bb = 0; size_t xidx = 0;
    if (tid >= 256 && tid < 288) {
      oi = (tid >> 4) & 1; bb = tid & 15;
      int te = (t >= 1) ? t - 1 : 0;
      xidx = ((size_t)(te * 64 + g * 16 + bb)) * 128 + 2 * cb + oi;
      asm volatile("global_load_dword %0, %1, off"
                   : "=v"(xv) : "v"(x + xidx) : "memory");
    }

    // per-wave producer gating: wave w_ needs only producer blocks
    // 8*w_ .. 8*w_+7 of its group (they own K-cols [128w_,128w_+128)).
    // No barrier after: each wave starts its loads/MFMA as soon as its
    // slice is published. Union over 8 waves == all 64 producers, and the
    // block's th-write sits behind SYNC1, so buffer reuse stays safe.
    {
      const int need = t + 1;
      int* sl = slots + g * 64 + w_ * 8 + (lane & 7);
      const bool act = lane < 8;
      int v = 0;
      while (true) {
        if (act) v = __hip_atomic_load(sl, __ATOMIC_RELAXED, __HIP_MEMORY_SCOPE_AGENT);
        if (__all(!act || v >= need)) break;
        __builtin_amdgcn_s_sleep(1);
      }
    }

    const unsigned int* thc = thp_base + (size_t)(g * 2 + (t & 1)) * 16384;

    // issue all A-fragment loads (th_t, packed hi|lo), 2 dwordx4 per K=32 chunk
    const unsigned int* ap = thc + (lane & 15) * 1024 + w_ * 128 + kb8;
    u32x4 a0a, a0b, a1a, a1b, a2a, a2b, a3a, a3b;
    LDA(a0a, a0b, ap);
    LDA(a1a, a1b, ap + 32);
    LDA(a2a, a2b, ap + 64);
    LDA(a3a, a3b, ap + 96);

    f32x4 accU = {0.f, 0.f, 0.f, 0.f};
    f32x4 accR = {0.f, 0.f, 0.f, 0.f};
    float po0 = 0.f, po1 = 0.f;

    PROC_KC(0, 6, a0a, a0b)
    PROC_KC(1, 4, a1a, a1b)
    PROC_KC(2, 2, a2a, a2b)
    PROC_KC(3, 0, a3a, a3b)

    // o-proj: reduce over kb (lane bits 4,5)
    po0 += __shfl_xor(po0, 16); po0 += __shfl_xor(po0, 32);
    po1 += __shfl_xor(po1, 16); po1 += __shfl_xor(po1, 32);

    // stash per-wave partials
    *(f32x4*)(redf + w_ * 512 +       lane * 4) = accU;
    *(f32x4*)(redf + w_ * 512 + 256 + lane * 4) = accR;
    if (lane < 16) {
      po_f[w_ * 32 +      lane] = po0;
      po_f[w_ * 32 + 16 + lane] = po1;
    }
    __syncthreads();   // SYNC1: all partials visible

    // error output for step t-1: off the tail, concurrent with gate math
    if (tid >= 256 && tid < 288 && t >= 1) {
      float sp = 0.f;
      #pragma unroll
      for (int w2 = 0; w2 < 8; ++w2) sp += po_f[w2 * 32 + oi * 16 + bb];
      out[xidx] = sp + bo_l[oi] - xv;
    }

    // gate math + h/th update; read the 8 wave-partials directly (no tot
    // stage, one barrier removed).  C frag: ci = ((b>>2)*16+sl)*4+(b&3).
    if (tid < 256 && t < TSTEPS) {
      int b = tid >> 4, sl = tid & 15;
      int ci = ((b >> 2) * 16 + sl) * 4 + (b & 3);
      float pu = bu_l[sl];
      float pr = br_l[sl];
      #pragma unroll
      for (int w2 = 0; w2 < 8; ++w2) {
        pu += redf[w2 * 512 +       ci];
        pr += redf[w2 * 512 + 256 + ci];
      }
      float u  = 1.f / (1.f + expf(-pu));
      float rr = tanhf(pr);
      float hv = h_lds[tid];
      float hn = u * hv + (1.f - u) * rr;
      h_lds[tid] = hn;
      float th = tanhf(hn);
      unsigned int hbits = __float_as_uint(th) & 0xffff0000u;
      float lof = th - __uint_as_float(hbits);
      unsigned int pk = hbits | (__float_as_uint(lof) >> 16);
      unsigned int* thn = thp_base + (size_t)(g * 2 + ((t + 1) & 1)) * 16384;
      stu_mall(thn + b * 1024 + sg0 + sl, pk);
    }

    // drain th stores, then post flag after the block-wide barrier
    asm volatile("s_waitcnt vmcnt(0)" ::: "memory");
    __syncthreads();   // SYNC3: all drains done; redf/h_lds safe for reuse
    if (tid == 0 && t < TSTEPS)
      __hip_atomic_store(&slots[blk], t + 2, __ATOMIC_RELAXED, __HIP_MEMORY_SCOPE_AGENT);
  }
}

extern "C" void kernel_launch(void* const* d_in, const int* in_sizes, int n_in,
                              void* d_out, int out_size, void* d_ws, size_t ws_size,
                              hipStream_t stream)
{
  const float* x      = (const float*)d_in[0];
  const float* h_init = (const float*)d_in[1];
  const float* w_o    = (const float*)d_in[2];
  const float* b_o    = (const float*)d_in[3];
  const float* w_u    = (const float*)d_in[4];
  const float* b_u    = (const float*)d_in[5];
  const float* w_r    = (const float*)d_in[6];
  const float* b_r    = (const float*)d_in[7];
  float* out = (float*)d_out;
  float* ws  = (float*)d_ws;

  hipFuncSetAttribute((const void*)ugrnn_persist,
                      hipFuncAttributeMaxDynamicSharedMemorySize, SMEM_BYTES);

  void* args[] = {
    (void*)&x, (void*)&h_init, (void*)&w_o, (void*)&b_o,
    (void*)&w_u, (void*)&b_u, (void*)&w_r, (void*)&b_r,
    (void*)&ws, (void*)&out
  };
  hipLaunchCooperativeKernel((const void*)ugrnn_persist,
                             dim3(NBLK), dim3(NTHR), args, SMEM_BYTES, stream);
}